// Round 5
// baseline (213.069 us; speedup 1.0000x reference)
//
#include <hip/hip_runtime.h>

typedef __attribute__((ext_vector_type(8))) short bf16x8;
typedef __attribute__((ext_vector_type(16))) float f32x16;

#define NROWS 32768
#define KC 1024
#define DD 128
#define EPS_GAP 1e-3f
#define FLT_BIG 3.4e38f

typedef const unsigned int __attribute__((address_space(1)))* gp1_t;
typedef unsigned int __attribute__((address_space(3)))* lp3_t;

__device__ __forceinline__ unsigned short f2bf(float f) {
    unsigned u = __float_as_uint(f);
    unsigned r = u + 0x7FFFu + ((u >> 16) & 1u);
    return (unsigned short)(r >> 16);
}
__device__ __forceinline__ float bf2f(unsigned short h) {
    return __uint_as_float(((unsigned)h) << 16);
}

// ================= prep: tiles + s2 only (codedist moved to k_post grid) =================
// 132 blocks: 0..127 bf16 hi/lo tile pack + eT, 128..131 s2. Block 128 zeroes loss acc.
__global__ __launch_bounds__(256) void k_prep(const float* __restrict__ e,
                                              unsigned short* __restrict__ a_sw,
                                              float* __restrict__ eT,
                                              float* __restrict__ s2g,
                                              double* __restrict__ loss_acc,
                                              unsigned int* __restrict__ done_cnt) {
    const int b = blockIdx.x, tid = threadIdx.x;
    if (b < 128) {
        const int t = b * 2 + (tid >> 7);     // tile 0..255
        const int ct = t >> 3, kd = t & 7;
        const int tt = tid & 127;
        const int m = tt & 31, dg = tt >> 5;
        const int c = ct * 32 + m;
        const int d0 = kd * 16 + dg * 4;
        float v[4]; short hi[4], lo[4];
        #pragma unroll
        for (int jj = 0; jj < 4; jj++) {
            float f = e[(size_t)(d0 + jj) * KC + c];
            v[jj] = f;
            unsigned short hh = f2bf(f);
            hi[jj] = (short)hh;
            lo[jj] = (short)f2bf(f - bf2f(hh));
        }
        const int h = dg >> 1, jb = (dg & 1) * 4;
        size_t base = ((size_t)(ct * 8 + kd) * 2) * 512 + (h * 32 + m) * 8 + jb;
        *(short4*)&a_sw[base]       = make_short4(hi[0], hi[1], hi[2], hi[3]);
        *(short4*)&a_sw[base + 512] = make_short4(lo[0], lo[1], lo[2], lo[3]);
        *(float4*)&eT[(size_t)c * DD + d0] = make_float4(v[0], v[1], v[2], v[3]);
    } else {
        if (b == 128 && tid == 0) { loss_acc[0] = 0.0; done_cnt[0] = 0u; }
        const int c = (b - 128) * 256 + tid;
        float s = 0.f;
        #pragma unroll 8
        for (int d = 0; d < DD; d++) { float f = e[(size_t)d * KC + c]; s = fmaf(f, f, s); }
        s2g[c] = s;
    }
}

// ======== main: persistent over K-half. 512 blocks = 2/CU exactly (R3 verified). ========
// Each block: 128 rows x 512 codes (8 chunks of 64), double-buffered 2x32KB LDS.
__global__ __launch_bounds__(256, 2) void k_main(const float* __restrict__ x,
                                                 const unsigned short* __restrict__ a_sw,
                                                 const float* __restrict__ s2g,
                                                 float* __restrict__ pv0,
                                                 float* __restrict__ pv1,
                                                 int* __restrict__ pi0) {
    __shared__ short es[2][16384];   // 2 x 32 KB double buffer
    __shared__ float s2s[512];

    const int tid = threadIdx.x;
    const int w = tid >> 6, lane = tid & 63;
    const int halfk = lane >> 5, col = lane & 31;
    const int gh = blockIdx.x & 1;          // K half: codes [gh*512, gh*512+512)
    const int rg = blockIdx.x >> 1;         // row group 0..255
    const int myrow = rg * 128 + w * 32 + col;

    // ---- stage chunk 0 of this half into buffer 0 ----
    {
        const char* src = (const char*)a_sw + (size_t)(gh * 8) * 32768;
        char* dst = (char*)&es[0][0];
        #pragma unroll
        for (int it = 0; it < 8; it++) {
            int off = (it * 256 + tid) * 16;
            __builtin_amdgcn_global_load_lds((gp1_t)(const void*)(src + off),
                                             (lp3_t)(void*)(dst + off), 16, 0, 0);
        }
    }
    s2s[tid]       = s2g[gh * 512 + tid];
    s2s[tid + 256] = s2g[gh * 512 + 256 + tid];

    // ---- x fragments: once per block (hides chunk-0 staging latency) ----
    const float* xr = x + (size_t)myrow * DD;
    bf16x8 xh[8], xl[8];
    #pragma unroll
    for (int kd = 0; kd < 8; kd++) {
        const float* p = xr + kd * 16 + halfk * 8;
        float4 a = *(const float4*)p;
        float4 b = *(const float4*)(p + 4);
        float v[8] = {a.x, a.y, a.z, a.w, b.x, b.y, b.z, b.w};
        #pragma unroll
        for (int j = 0; j < 8; j++) {
            unsigned short h = f2bf(v[j]);
            xh[kd][j] = (short)h;
            xl[kd][j] = (short)f2bf(v[j] - bf2f(h));
        }
    }
    __syncthreads();   // chunk 0 staged + s2s ready

    float bv0 = FLT_BIG, bv1 = FLT_BIG;
    int bi0 = 0x7fffffff;

    #pragma unroll 1
    for (int c = 0; c < 8; c++) {
        const int cb = c & 1;
        // prefetch next chunk into the other buffer (in flight during compute)
        if (c < 7) {
            const char* src = (const char*)a_sw + (size_t)(gh * 8 + c + 1) * 32768;
            char* dst = (char*)&es[cb ^ 1][0];
            #pragma unroll
            for (int it = 0; it < 8; it++) {
                int off = (it * 256 + tid) * 16;
                __builtin_amdgcn_global_load_lds((gp1_t)(const void*)(src + off),
                                                 (lp3_t)(void*)(dst + off), 16, 0, 0);
            }
        }

        #pragma unroll 1
        for (int ct = 0; ct < 2; ct++) {
            f32x16 accA, accB, accC;
            #pragma unroll
            for (int r = 0; r < 16; r++) { accA[r] = 0.f; accB[r] = 0.f; accC[r] = 0.f; }

            #pragma unroll
            for (int kd = 0; kd < 8; kd++) {
                const short* fp = &es[cb][((ct * 8 + kd) * 2) * 512 + lane * 8];
                bf16x8 ahi = *(const bf16x8*)fp;
                bf16x8 alo = *(const bf16x8*)(fp + 512);
                accA = __builtin_amdgcn_mfma_f32_32x32x16_bf16(ahi, xh[kd], accA, 0, 0, 0);
                accB = __builtin_amdgcn_mfma_f32_32x32x16_bf16(alo, xh[kd], accB, 0, 0, 0);
                accC = __builtin_amdgcn_mfma_f32_32x32x16_bf16(ahi, xl[kd], accC, 0, 0, 0);
            }

            int lcb = c * 64 + ct * 32 + 4 * halfk;   // local code base 0..511
            #pragma unroll
            for (int g8 = 0; g8 < 4; g8++) {
                float4 s2v = *(const float4*)&s2s[lcb + g8 * 8];
                const float* s2p = (const float*)&s2v;
                #pragma unroll
                for (int q = 0; q < 4; q++) {
                    int r = g8 * 4 + q;
                    float sim = (accA[r] + accB[r]) + accC[r];
                    float dv = fmaf(-2.f, sim, s2p[q]);
                    int ci = gh * 512 + lcb + g8 * 8 + q;
                    bool lt = dv < bv0;
                    bv1 = fminf(bv1, fmaxf(bv0, dv));
                    bv0 = fminf(bv0, dv);
                    bi0 = lt ? ci : bi0;
                }
            }
        }
        __syncthreads();   // drains next-chunk staging + protects buffer reuse
    }

    float u0 = __shfl_xor(bv0, 32, 64);
    float u1 = __shfl_xor(bv1, 32, 64);
    int   j0 = __shfl_xor(bi0, 32, 64);
    float v0, v1; int i0;
    if (u0 < bv0 || (u0 == bv0 && j0 < bi0)) { v0 = u0; i0 = j0; v1 = fminf(u1, bv0); }
    else                                     { v0 = bv0; i0 = bi0; v1 = fminf(bv1, u0); }

    if (lane < 32) {
        size_t o = (size_t)myrow * 2 + gh;    // 2 partials per row
        pv0[o] = v0; pv1[o] = v1; pi0[o] = i0;
    }
}

// ==== post: blocks 0..511 codedist (out_scales); 512..2559 merge+gather+loss+finalize ====
// 2560 blocks x 128 threads. Codedist first so it overlaps the latency-bound gather role.
__global__ __launch_bounds__(128) void k_post(const float* __restrict__ x,
                                              const float* __restrict__ e,
                                              const float* __restrict__ eT,
                                              const float* __restrict__ s2g,
                                              const float* __restrict__ pv0,
                                              const float* __restrict__ pv1,
                                              const int* __restrict__ pi0,
                                              float* __restrict__ out_q,
                                              float* __restrict__ out_scales,
                                              float* __restrict__ out_loss,
                                              double* __restrict__ loss_acc,
                                              unsigned int* __restrict__ done_cnt) {
    const int tid = threadIdx.x;
    const int w = tid >> 6, lane = tid & 63;

    if (blockIdx.x < 512) {
        // ---- codedist role: 2 codes per block, exact fp32 diff-square, 128 threads ----
        __shared__ float ekA[DD], ekB[DD];
        __shared__ float r0s[2][2], r1s[2][2];
        __shared__ float scs[2];
        const int kb = blockIdx.x * 2;
        ekA[tid] = e[(size_t)tid * KC + kb];
        ekB[tid] = e[(size_t)tid * KC + kb + 1];
        __syncthreads();
        const int j0 = tid * 8;                 // 8 codes per thread
        float da[2][8];
        #pragma unroll
        for (int ki = 0; ki < 2; ki++)
            #pragma unroll
            for (int jj = 0; jj < 8; jj++) da[ki][jj] = 0.f;
        #pragma unroll 4
        for (int d = 0; d < DD; d++) {
            float4 ev0 = *(const float4*)&e[(size_t)d * KC + j0];
            float4 ev1 = *(const float4*)&e[(size_t)d * KC + j0 + 4];
            float e0 = ekA[d], e1 = ekB[d];
            const float* p0 = (const float*)&ev0;
            const float* p1 = (const float*)&ev1;
            #pragma unroll
            for (int jj = 0; jj < 4; jj++) {
                float t0 = e0 - p0[jj], t1 = e1 - p0[jj];
                da[0][jj] = fmaf(t0, t0, da[0][jj]);
                da[1][jj] = fmaf(t1, t1, da[1][jj]);
                float t2 = e0 - p1[jj], t3 = e1 - p1[jj];
                da[0][jj + 4] = fmaf(t2, t2, da[0][jj + 4]);
                da[1][jj + 4] = fmaf(t3, t3, da[1][jj + 4]);
            }
        }
        float m0[2] = {FLT_BIG, FLT_BIG}, m1[2] = {FLT_BIG, FLT_BIG};
        #pragma unroll
        for (int ki = 0; ki < 2; ki++)
            #pragma unroll
            for (int jj = 0; jj < 8; jj++) {
                float dd = da[ki][jj];
                if (dd < m0[ki]) { m1[ki] = m0[ki]; m0[ki] = dd; }
                else if (dd < m1[ki]) m1[ki] = dd;
            }
        #pragma unroll
        for (int msk = 1; msk < 64; msk <<= 1) {
            #pragma unroll
            for (int ki = 0; ki < 2; ki++) {
                float u0 = __shfl_xor(m0[ki], msk, 64);
                float u1 = __shfl_xor(m1[ki], msk, 64);
                if (u0 < m0[ki]) { m1[ki] = fminf(m0[ki], u1); m0[ki] = u0; }
                else             { m1[ki] = fminf(m1[ki], u0); }
            }
        }
        if (lane == 0) {
            r0s[0][w] = m0[0]; r1s[0][w] = m1[0];
            r0s[1][w] = m0[1]; r1s[1][w] = m1[1];
        }
        __syncthreads();
        if (tid < 2) {
            float a0, a1;
            float v00 = r0s[tid][0], v10 = r1s[tid][0];
            float v01 = r0s[tid][1], v11 = r1s[tid][1];
            if (v01 < v00) { a0 = v01; a1 = fminf(v00, v11); }
            else           { a0 = v00; a1 = fminf(v10, v01); }
            (void)a0;
            scs[tid] = a1 * (1.0f / 64.0f);   // second_smallest / (D/2)
        }
        __syncthreads();
        out_scales[(size_t)kb * DD + tid]       = scs[0];
        out_scales[(size_t)(kb + 1) * DD + tid] = scs[1];
        return;
    }

    // ---- gather role ----
    __shared__ int   flist_l[16];
    __shared__ int   cnt;
    __shared__ float xrow[DD];
    __shared__ float rv[128];
    __shared__ int   ri[128];
    __shared__ int   kfix;
    __shared__ float wsum[2];
    const int bid = blockIdx.x - 512;
    const int row0 = bid * 16;
    const int rl = tid >> 3;                 // local row 0..15
    const int seg = (tid & 7) * 16;          // 16 consecutive floats

    if (tid == 0) cnt = 0;

    // ---- prefetch x segment ----
    const size_t grow = (size_t)(row0 + rl);
    float4 xv[4];
    {
        const float* xp = x + grow * DD + seg;
        #pragma unroll
        for (int i = 0; i < 4; i++) xv[i] = *(const float4*)(xp + i * 4);
    }

    // ---- merge 2 half-partials (sequential; gh=0 indices lower, tie keeps first) ----
    float v0, v1; int i0;
    {
        size_t o = grow * 2;
        float a0 = pv0[o],     a1 = pv1[o];     int ai = pi0[o];
        float b0 = pv0[o + 1], b1 = pv1[o + 1]; int bi = pi0[o + 1];
        if (b0 < a0) { v0 = b0; i0 = bi; v1 = fminf(b1, a0); }
        else         { v0 = a0; i0 = ai; v1 = fminf(a1, b0); }
    }
    const int flagged = (v1 - v0 < EPS_GAP) ? 1 : 0;
    if ((tid & 7) == 0 && flagged) { int s = atomicAdd(&cnt, 1); flist_l[s] = rl; }

    // ---- gather + loss (skip flagged rows; rewritten in fix phase) ----
    float lsum = 0.f;
    if (!flagged) {
        const float* qp = eT + (size_t)i0 * DD + seg;
        float* op = out_q + grow * DD + seg;
        #pragma unroll
        for (int i = 0; i < 4; i++) {
            float4 q = *(const float4*)(qp + i * 4);
            *(float4*)(op + i * 4) = q;
            float f0 = q.x - xv[i].x, f1 = q.y - xv[i].y;
            float f2 = q.z - xv[i].z, f3 = q.w - xv[i].w;
            lsum = fmaf(f0, f0, lsum); lsum = fmaf(f1, f1, lsum);
            lsum = fmaf(f2, f2, lsum); lsum = fmaf(f3, f3, lsum);
        }
    }
    __syncthreads();

    // ---- exact fp32 re-argmin for flagged rows (rare, block-uniform) ----
    const int nf = cnt;
    for (int fi = 0; fi < nf; fi++) {
        const int r = flist_l[fi];
        if (tid < 32) ((float4*)xrow)[tid] = ((const float4*)(x + (size_t)(row0 + r) * DD))[tid];
        __syncthreads();
        int c0 = tid * 8;
        float s[8];
        #pragma unroll
        for (int j = 0; j < 8; j++) s[j] = 0.f;
        #pragma unroll 8
        for (int d = 0; d < DD; d++) {
            float xd = xrow[d];
            float4 ev0 = *(const float4*)(e + (size_t)d * KC + c0);
            float4 ev1 = *(const float4*)(e + (size_t)d * KC + c0 + 4);
            s[0] = fmaf(xd, ev0.x, s[0]); s[1] = fmaf(xd, ev0.y, s[1]);
            s[2] = fmaf(xd, ev0.z, s[2]); s[3] = fmaf(xd, ev0.w, s[3]);
            s[4] = fmaf(xd, ev1.x, s[4]); s[5] = fmaf(xd, ev1.y, s[5]);
            s[6] = fmaf(xd, ev1.z, s[6]); s[7] = fmaf(xd, ev1.w, s[7]);
        }
        float bv = FLT_BIG; int bi = 0x7fffffff;
        #pragma unroll
        for (int j = 0; j < 8; j++) {
            float dv = s2g[c0 + j] - 2.f * s[j];
            if (dv < bv) { bv = dv; bi = c0 + j; }
        }
        rv[tid] = bv; ri[tid] = bi;
        __syncthreads();
        if (tid == 0) {
            float b = rv[0]; int bidx = ri[0];
            for (int t = 1; t < 128; t++)
                if (rv[t] < b) { b = rv[t]; bidx = ri[t]; }
            kfix = bidx;
        }
        __syncthreads();
        {
            float q = eT[(size_t)kfix * DD + tid];
            float xd = xrow[tid];
            out_q[(size_t)(row0 + r) * DD + tid] = q;
            float f = q - xd;
            lsum = fmaf(f, f, lsum);
        }
        __syncthreads();
    }

    // ---- per-block partial loss -> device-scope atomic accumulate + last-block finalize ----
    #pragma unroll
    for (int off = 32; off > 0; off >>= 1) lsum += __shfl_down(lsum, off, 64);
    if (lane == 0) wsum[w] = lsum;
    __syncthreads();
    if (tid == 0) {
        atomicAdd(loss_acc, (double)(wsum[0] + wsum[1]));
        __threadfence();
        unsigned int old = atomicAdd(done_cnt, 1u);
        if (old == 2047u) {
            double m = atomicAdd(loss_acc, 0.0) / 4194304.0;   // atomic read sees all adds
            out_loss[0] = (float)(0.25 * m + m);
        }
    }
}

extern "C" void kernel_launch(void* const* d_in, const int* in_sizes, int n_in,
                              void* d_out, int out_size, void* d_ws, size_t ws_size,
                              hipStream_t stream) {
    const float* x = (const float*)d_in[0];
    const float* e = (const float*)d_in[1];
    float* out_q      = (float*)d_out;
    float* out_loss   = out_q + (size_t)NROWS * DD;
    float* out_scales = out_loss + 1;

    char* ws = (char*)d_ws;
    float*  s2g            = (float*)(ws + 1024);
    float*  eT             = (float*)(ws + 8192);
    unsigned short* a_sw   = (unsigned short*)(ws + 532480);
    float*  pv0            = (float*)(ws + 1056768);   // 32768*2*4 = 256 KB
    float*  pv1            = (float*)(ws + 1318912);   // 256 KB
    int*    pi0            = (int*)(ws + 1581056);     // 256 KB
    double* loss_acc       = (double*)(ws + 1843200);
    unsigned int* done_cnt = (unsigned int*)(ws + 1843208);

    k_prep<<<132, 256, 0, stream>>>(e, a_sw, eT, s2g, loss_acc, done_cnt);
    k_main<<<512, 256, 0, stream>>>(x, a_sw, s2g, pv0, pv1, pi0);
    k_post<<<2560, 128, 0, stream>>>(x, e, eT, s2g, pv0, pv1, pi0,
                                     out_q, out_scales, out_loss, loss_acc, done_cnt);
}

// Round 6
// 145.147 us; speedup vs baseline: 1.4680x; 1.4680x over previous
//
#include <hip/hip_runtime.h>

typedef __attribute__((ext_vector_type(8))) short bf16x8;
typedef __attribute__((ext_vector_type(16))) float f32x16;

#define NROWS 32768
#define KC 1024
#define DD 128
#define EPS_GAP 1e-3f
#define FLT_BIG 3.4e38f

typedef const unsigned int __attribute__((address_space(1)))* gp1_t;
typedef unsigned int __attribute__((address_space(3)))* lp3_t;

__device__ __forceinline__ unsigned short f2bf(float f) {
    unsigned u = __float_as_uint(f);
    unsigned r = u + 0x7FFFu + ((u >> 16) & 1u);
    return (unsigned short)(r >> 16);
}
__device__ __forceinline__ float bf2f(unsigned short h) {
    return __uint_as_float(((unsigned)h) << 16);
}

// ================= prep: tiles + s2 only (codedist lives in k_post grid) =================
// 132 blocks: 0..127 bf16 hi/lo tile pack + eT, 128..131 s2.
__global__ __launch_bounds__(256) void k_prep(const float* __restrict__ e,
                                              unsigned short* __restrict__ a_sw,
                                              float* __restrict__ eT,
                                              float* __restrict__ s2g) {
    const int b = blockIdx.x, tid = threadIdx.x;
    if (b < 128) {
        const int t = b * 2 + (tid >> 7);     // tile 0..255
        const int ct = t >> 3, kd = t & 7;
        const int tt = tid & 127;
        const int m = tt & 31, dg = tt >> 5;
        const int c = ct * 32 + m;
        const int d0 = kd * 16 + dg * 4;
        float v[4]; short hi[4], lo[4];
        #pragma unroll
        for (int jj = 0; jj < 4; jj++) {
            float f = e[(size_t)(d0 + jj) * KC + c];
            v[jj] = f;
            unsigned short hh = f2bf(f);
            hi[jj] = (short)hh;
            lo[jj] = (short)f2bf(f - bf2f(hh));
        }
        const int h = dg >> 1, jb = (dg & 1) * 4;
        size_t base = ((size_t)(ct * 8 + kd) * 2) * 512 + (h * 32 + m) * 8 + jb;
        *(short4*)&a_sw[base]       = make_short4(hi[0], hi[1], hi[2], hi[3]);
        *(short4*)&a_sw[base + 512] = make_short4(lo[0], lo[1], lo[2], lo[3]);
        *(float4*)&eT[(size_t)c * DD + d0] = make_float4(v[0], v[1], v[2], v[3]);
    } else {
        const int c = (b - 128) * 256 + tid;
        float s = 0.f;
        #pragma unroll 8
        for (int d = 0; d < DD; d++) { float f = e[(size_t)d * KC + c]; s = fmaf(f, f, s); }
        s2g[c] = s;
    }
}

// ======== main: persistent over K-half. 512 blocks = 2/CU exactly (R3 verified). ========
// Each block: 128 rows x 512 codes (8 chunks of 64), double-buffered 2x32KB LDS.
__global__ __launch_bounds__(256, 2) void k_main(const float* __restrict__ x,
                                                 const unsigned short* __restrict__ a_sw,
                                                 const float* __restrict__ s2g,
                                                 float* __restrict__ pv0,
                                                 float* __restrict__ pv1,
                                                 int* __restrict__ pi0) {
    __shared__ short es[2][16384];   // 2 x 32 KB double buffer
    __shared__ float s2s[512];

    const int tid = threadIdx.x;
    const int w = tid >> 6, lane = tid & 63;
    const int halfk = lane >> 5, col = lane & 31;
    const int gh = blockIdx.x & 1;          // K half: codes [gh*512, gh*512+512)
    const int rg = blockIdx.x >> 1;         // row group 0..255
    const int myrow = rg * 128 + w * 32 + col;

    // ---- stage chunk 0 of this half into buffer 0 ----
    {
        const char* src = (const char*)a_sw + (size_t)(gh * 8) * 32768;
        char* dst = (char*)&es[0][0];
        #pragma unroll
        for (int it = 0; it < 8; it++) {
            int off = (it * 256 + tid) * 16;
            __builtin_amdgcn_global_load_lds((gp1_t)(const void*)(src + off),
                                             (lp3_t)(void*)(dst + off), 16, 0, 0);
        }
    }
    s2s[tid]       = s2g[gh * 512 + tid];
    s2s[tid + 256] = s2g[gh * 512 + 256 + tid];

    // ---- x fragments: once per block (hides chunk-0 staging latency) ----
    const float* xr = x + (size_t)myrow * DD;
    bf16x8 xh[8], xl[8];
    #pragma unroll
    for (int kd = 0; kd < 8; kd++) {
        const float* p = xr + kd * 16 + halfk * 8;
        float4 a = *(const float4*)p;
        float4 b = *(const float4*)(p + 4);
        float v[8] = {a.x, a.y, a.z, a.w, b.x, b.y, b.z, b.w};
        #pragma unroll
        for (int j = 0; j < 8; j++) {
            unsigned short h = f2bf(v[j]);
            xh[kd][j] = (short)h;
            xl[kd][j] = (short)f2bf(v[j] - bf2f(h));
        }
    }
    __syncthreads();   // chunk 0 staged + s2s ready

    float bv0 = FLT_BIG, bv1 = FLT_BIG;
    int bi0 = 0x7fffffff;

    #pragma unroll 1
    for (int c = 0; c < 8; c++) {
        const int cb = c & 1;
        // prefetch next chunk into the other buffer (in flight during compute)
        if (c < 7) {
            const char* src = (const char*)a_sw + (size_t)(gh * 8 + c + 1) * 32768;
            char* dst = (char*)&es[cb ^ 1][0];
            #pragma unroll
            for (int it = 0; it < 8; it++) {
                int off = (it * 256 + tid) * 16;
                __builtin_amdgcn_global_load_lds((gp1_t)(const void*)(src + off),
                                                 (lp3_t)(void*)(dst + off), 16, 0, 0);
            }
        }

        #pragma unroll 1
        for (int ct = 0; ct < 2; ct++) {
            f32x16 accA, accB, accC;
            #pragma unroll
            for (int r = 0; r < 16; r++) { accA[r] = 0.f; accB[r] = 0.f; accC[r] = 0.f; }

            #pragma unroll
            for (int kd = 0; kd < 8; kd++) {
                const short* fp = &es[cb][((ct * 8 + kd) * 2) * 512 + lane * 8];
                bf16x8 ahi = *(const bf16x8*)fp;
                bf16x8 alo = *(const bf16x8*)(fp + 512);
                accA = __builtin_amdgcn_mfma_f32_32x32x16_bf16(ahi, xh[kd], accA, 0, 0, 0);
                accB = __builtin_amdgcn_mfma_f32_32x32x16_bf16(alo, xh[kd], accB, 0, 0, 0);
                accC = __builtin_amdgcn_mfma_f32_32x32x16_bf16(ahi, xl[kd], accC, 0, 0, 0);
            }

            int lcb = c * 64 + ct * 32 + 4 * halfk;   // local code base 0..511
            #pragma unroll
            for (int g8 = 0; g8 < 4; g8++) {
                float4 s2v = *(const float4*)&s2s[lcb + g8 * 8];
                const float* s2p = (const float*)&s2v;
                #pragma unroll
                for (int q = 0; q < 4; q++) {
                    int r = g8 * 4 + q;
                    float sim = (accA[r] + accB[r]) + accC[r];
                    float dv = fmaf(-2.f, sim, s2p[q]);
                    int ci = gh * 512 + lcb + g8 * 8 + q;
                    bool lt = dv < bv0;
                    bv1 = fminf(bv1, fmaxf(bv0, dv));
                    bv0 = fminf(bv0, dv);
                    bi0 = lt ? ci : bi0;
                }
            }
        }
        __syncthreads();   // drains next-chunk staging + protects buffer reuse
    }

    float u0 = __shfl_xor(bv0, 32, 64);
    float u1 = __shfl_xor(bv1, 32, 64);
    int   j0 = __shfl_xor(bi0, 32, 64);
    float v0, v1; int i0;
    if (u0 < bv0 || (u0 == bv0 && j0 < bi0)) { v0 = u0; i0 = j0; v1 = fminf(u1, bv0); }
    else                                     { v0 = bv0; i0 = bi0; v1 = fminf(bv1, u0); }

    if (lane < 32) {
        size_t o = (size_t)myrow * 2 + gh;    // 2 partials per row
        pv0[o] = v0; pv1[o] = v1; pi0[o] = i0;
    }
}

// ==== post: blocks 0..511 codedist (out_scales); 512..2559 merge+gather+loss partial ====
// 2560 blocks x 128 threads. Plain partial[] store (NO device-scope fence/atomics --
// the R5 atomic+threadfence finalize caused an L2-writeback storm: 140us tail).
__global__ __launch_bounds__(128) void k_post(const float* __restrict__ x,
                                              const float* __restrict__ e,
                                              const float* __restrict__ eT,
                                              const float* __restrict__ s2g,
                                              const float* __restrict__ pv0,
                                              const float* __restrict__ pv1,
                                              const int* __restrict__ pi0,
                                              float* __restrict__ out_q,
                                              float* __restrict__ out_scales,
                                              double* __restrict__ partial) {
    const int tid = threadIdx.x;
    const int w = tid >> 6, lane = tid & 63;

    if (blockIdx.x < 512) {
        // ---- codedist role: 2 codes per block, exact fp32 diff-square, 128 threads ----
        __shared__ float ekA[DD], ekB[DD];
        __shared__ float r0s[2][2], r1s[2][2];
        __shared__ float scs[2];
        const int kb = blockIdx.x * 2;
        ekA[tid] = e[(size_t)tid * KC + kb];
        ekB[tid] = e[(size_t)tid * KC + kb + 1];
        __syncthreads();
        const int j0 = tid * 8;                 // 8 codes per thread
        float da[2][8];
        #pragma unroll
        for (int ki = 0; ki < 2; ki++)
            #pragma unroll
            for (int jj = 0; jj < 8; jj++) da[ki][jj] = 0.f;
        #pragma unroll 4
        for (int d = 0; d < DD; d++) {
            float4 ev0 = *(const float4*)&e[(size_t)d * KC + j0];
            float4 ev1 = *(const float4*)&e[(size_t)d * KC + j0 + 4];
            float e0 = ekA[d], e1 = ekB[d];
            const float* p0 = (const float*)&ev0;
            const float* p1 = (const float*)&ev1;
            #pragma unroll
            for (int jj = 0; jj < 4; jj++) {
                float t0 = e0 - p0[jj], t1 = e1 - p0[jj];
                da[0][jj] = fmaf(t0, t0, da[0][jj]);
                da[1][jj] = fmaf(t1, t1, da[1][jj]);
                float t2 = e0 - p1[jj], t3 = e1 - p1[jj];
                da[0][jj + 4] = fmaf(t2, t2, da[0][jj + 4]);
                da[1][jj + 4] = fmaf(t3, t3, da[1][jj + 4]);
            }
        }
        float m0[2] = {FLT_BIG, FLT_BIG}, m1[2] = {FLT_BIG, FLT_BIG};
        #pragma unroll
        for (int ki = 0; ki < 2; ki++)
            #pragma unroll
            for (int jj = 0; jj < 8; jj++) {
                float dd = da[ki][jj];
                if (dd < m0[ki]) { m1[ki] = m0[ki]; m0[ki] = dd; }
                else if (dd < m1[ki]) m1[ki] = dd;
            }
        #pragma unroll
        for (int msk = 1; msk < 64; msk <<= 1) {
            #pragma unroll
            for (int ki = 0; ki < 2; ki++) {
                float u0 = __shfl_xor(m0[ki], msk, 64);
                float u1 = __shfl_xor(m1[ki], msk, 64);
                if (u0 < m0[ki]) { m1[ki] = fminf(m0[ki], u1); m0[ki] = u0; }
                else             { m1[ki] = fminf(m1[ki], u0); }
            }
        }
        if (lane == 0) {
            r0s[0][w] = m0[0]; r1s[0][w] = m1[0];
            r0s[1][w] = m0[1]; r1s[1][w] = m1[1];
        }
        __syncthreads();
        if (tid < 2) {
            float a1;
            float v00 = r0s[tid][0], v10 = r1s[tid][0];
            float v01 = r0s[tid][1], v11 = r1s[tid][1];
            if (v01 < v00) { a1 = fminf(v00, v11); }
            else           { a1 = fminf(v10, v01); }
            scs[tid] = a1 * (1.0f / 64.0f);   // second_smallest / (D/2)
        }
        __syncthreads();
        out_scales[(size_t)kb * DD + tid]       = scs[0];
        out_scales[(size_t)(kb + 1) * DD + tid] = scs[1];
        return;
    }

    // ---- gather role ----
    __shared__ int   flist_l[16];
    __shared__ int   cnt;
    __shared__ float xrow[DD];
    __shared__ float rv[128];
    __shared__ int   ri[128];
    __shared__ int   kfix;
    __shared__ float wsum[2];
    const int bid = blockIdx.x - 512;
    const int row0 = bid * 16;
    const int rl = tid >> 3;                 // local row 0..15
    const int seg = (tid & 7) * 16;          // 16 consecutive floats

    if (tid == 0) cnt = 0;

    // ---- prefetch x segment ----
    const size_t grow = (size_t)(row0 + rl);
    float4 xv[4];
    {
        const float* xp = x + grow * DD + seg;
        #pragma unroll
        for (int i = 0; i < 4; i++) xv[i] = *(const float4*)(xp + i * 4);
    }

    // ---- merge 2 half-partials (sequential; gh=0 indices lower, tie keeps first) ----
    float v0, v1; int i0;
    {
        size_t o = grow * 2;
        float a0 = pv0[o],     a1 = pv1[o];     int ai = pi0[o];
        float b0 = pv0[o + 1], b1 = pv1[o + 1]; int bi = pi0[o + 1];
        if (b0 < a0) { v0 = b0; i0 = bi; v1 = fminf(b1, a0); }
        else         { v0 = a0; i0 = ai; v1 = fminf(a1, b0); }
    }
    const int flagged = (v1 - v0 < EPS_GAP) ? 1 : 0;
    if ((tid & 7) == 0 && flagged) { int s = atomicAdd(&cnt, 1); flist_l[s] = rl; }

    // ---- gather + loss (skip flagged rows; rewritten in fix phase) ----
    float lsum = 0.f;
    if (!flagged) {
        const float* qp = eT + (size_t)i0 * DD + seg;
        float* op = out_q + grow * DD + seg;
        #pragma unroll
        for (int i = 0; i < 4; i++) {
            float4 q = *(const float4*)(qp + i * 4);
            *(float4*)(op + i * 4) = q;
            float f0 = q.x - xv[i].x, f1 = q.y - xv[i].y;
            float f2 = q.z - xv[i].z, f3 = q.w - xv[i].w;
            lsum = fmaf(f0, f0, lsum); lsum = fmaf(f1, f1, lsum);
            lsum = fmaf(f2, f2, lsum); lsum = fmaf(f3, f3, lsum);
        }
    }
    __syncthreads();

    // ---- exact fp32 re-argmin for flagged rows (rare, block-uniform) ----
    const int nf = cnt;
    for (int fi = 0; fi < nf; fi++) {
        const int r = flist_l[fi];
        if (tid < 32) ((float4*)xrow)[tid] = ((const float4*)(x + (size_t)(row0 + r) * DD))[tid];
        __syncthreads();
        int c0 = tid * 8;
        float s[8];
        #pragma unroll
        for (int j = 0; j < 8; j++) s[j] = 0.f;
        #pragma unroll 8
        for (int d = 0; d < DD; d++) {
            float xd = xrow[d];
            float4 ev0 = *(const float4*)(e + (size_t)d * KC + c0);
            float4 ev1 = *(const float4*)(e + (size_t)d * KC + c0 + 4);
            s[0] = fmaf(xd, ev0.x, s[0]); s[1] = fmaf(xd, ev0.y, s[1]);
            s[2] = fmaf(xd, ev0.z, s[2]); s[3] = fmaf(xd, ev0.w, s[3]);
            s[4] = fmaf(xd, ev1.x, s[4]); s[5] = fmaf(xd, ev1.y, s[5]);
            s[6] = fmaf(xd, ev1.z, s[6]); s[7] = fmaf(xd, ev1.w, s[7]);
        }
        float bv = FLT_BIG; int bi = 0x7fffffff;
        #pragma unroll
        for (int j = 0; j < 8; j++) {
            float dv = s2g[c0 + j] - 2.f * s[j];
            if (dv < bv) { bv = dv; bi = c0 + j; }
        }
        rv[tid] = bv; ri[tid] = bi;
        __syncthreads();
        if (tid == 0) {
            float b = rv[0]; int bidx = ri[0];
            for (int t = 1; t < 128; t++)
                if (rv[t] < b) { b = rv[t]; bidx = ri[t]; }
            kfix = bidx;
        }
        __syncthreads();
        {
            float q = eT[(size_t)kfix * DD + tid];
            float xd = xrow[tid];
            out_q[(size_t)(row0 + r) * DD + tid] = q;
            float f = q - xd;
            lsum = fmaf(f, f, lsum);
        }
        __syncthreads();
    }

    // ---- per-block partial loss: plain store, no atomics, no fence ----
    #pragma unroll
    for (int off = 32; off > 0; off >>= 1) lsum += __shfl_down(lsum, off, 64);
    if (lane == 0) wsum[w] = lsum;
    __syncthreads();
    if (tid == 0)
        partial[bid] = (double)(wsum[0] + wsum[1]);
}

// ================= fin: sum 2048 partials, write loss =================
__global__ __launch_bounds__(256) void k_fin(const double* __restrict__ partial,
                                             float* __restrict__ out_loss) {
    __shared__ double wred[4];
    const int tid = threadIdx.x;
    const int w = tid >> 6, lane = tid & 63;
    double s = 0.0;
    #pragma unroll
    for (int i = 0; i < 8; i++) s += partial[i * 256 + tid];
    #pragma unroll
    for (int off = 32; off > 0; off >>= 1)
        s += __shfl_down(s, off, 64);
    if (lane == 0) wred[w] = s;
    __syncthreads();
    if (tid == 0) {
        double m = ((wred[0] + wred[1]) + (wred[2] + wred[3])) / 4194304.0;
        out_loss[0] = (float)(0.25 * m + m);
    }
}

extern "C" void kernel_launch(void* const* d_in, const int* in_sizes, int n_in,
                              void* d_out, int out_size, void* d_ws, size_t ws_size,
                              hipStream_t stream) {
    const float* x = (const float*)d_in[0];
    const float* e = (const float*)d_in[1];
    float* out_q      = (float*)d_out;
    float* out_loss   = out_q + (size_t)NROWS * DD;
    float* out_scales = out_loss + 1;

    char* ws = (char*)d_ws;
    float*  s2g            = (float*)(ws + 1024);
    float*  eT             = (float*)(ws + 8192);
    unsigned short* a_sw   = (unsigned short*)(ws + 532480);
    float*  pv0            = (float*)(ws + 1056768);   // 32768*2*4 = 256 KB
    float*  pv1            = (float*)(ws + 1318912);   // 256 KB
    int*    pi0            = (int*)(ws + 1581056);     // 256 KB
    double* partial        = (double*)(ws + 1843200);  // 2048*8 = 16 KB

    k_prep<<<132, 256, 0, stream>>>(e, a_sw, eT, s2g);
    k_main<<<512, 256, 0, stream>>>(x, a_sw, s2g, pv0, pv1, pi0);
    k_post<<<2560, 128, 0, stream>>>(x, e, eT, s2g, pv0, pv1, pi0,
                                     out_q, out_scales, partial);
    k_fin<<<1, 256, 0, stream>>>(partial, out_loss);
}

// Round 7
// 144.945 us; speedup vs baseline: 1.4700x; 1.0014x over previous
//
#include <hip/hip_runtime.h>

typedef __attribute__((ext_vector_type(8))) short bf16x8;
typedef __attribute__((ext_vector_type(16))) float f32x16;

#define NROWS 32768
#define KC 1024
#define DD 128
#define EPS_GAP 2.5e-4f
#define FLT_BIG 3.4e38f

typedef const unsigned int __attribute__((address_space(1)))* gp1_t;
typedef unsigned int __attribute__((address_space(3)))* lp3_t;

__device__ __forceinline__ unsigned short f2bf(float f) {
    unsigned u = __float_as_uint(f);
    unsigned r = u + 0x7FFFu + ((u >> 16) & 1u);
    return (unsigned short)(r >> 16);
}
__device__ __forceinline__ float bf2f(unsigned short h) {
    return __uint_as_float(((unsigned)h) << 16);
}

// ================= prep: tiles + s2 =================
// 132 blocks: 0..127 bf16 hi/lo tile pack + eT, 128..131 s2.
__global__ __launch_bounds__(256) void k_prep(const float* __restrict__ e,
                                              unsigned short* __restrict__ a_sw,
                                              float* __restrict__ eT,
                                              float* __restrict__ s2g) {
    const int b = blockIdx.x, tid = threadIdx.x;
    if (b < 128) {
        const int t = b * 2 + (tid >> 7);     // tile 0..255
        const int ct = t >> 3, kd = t & 7;
        const int tt = tid & 127;
        const int m = tt & 31, dg = tt >> 5;
        const int c = ct * 32 + m;
        const int d0 = kd * 16 + dg * 4;
        float v[4]; short hi[4], lo[4];
        #pragma unroll
        for (int jj = 0; jj < 4; jj++) {
            float f = e[(size_t)(d0 + jj) * KC + c];
            v[jj] = f;
            unsigned short hh = f2bf(f);
            hi[jj] = (short)hh;
            lo[jj] = (short)f2bf(f - bf2f(hh));
        }
        const int h = dg >> 1, jb = (dg & 1) * 4;
        size_t base = ((size_t)(ct * 8 + kd) * 2) * 512 + (h * 32 + m) * 8 + jb;
        *(short4*)&a_sw[base]       = make_short4(hi[0], hi[1], hi[2], hi[3]);
        *(short4*)&a_sw[base + 512] = make_short4(lo[0], lo[1], lo[2], lo[3]);
        *(float4*)&eT[(size_t)c * DD + d0] = make_float4(v[0], v[1], v[2], v[3]);
    } else {
        const int c = (b - 128) * 256 + tid;
        float s = 0.f;
        #pragma unroll 8
        for (int d = 0; d < DD; d++) { float f = e[(size_t)d * KC + c]; s = fmaf(f, f, s); }
        s2g[c] = s;
    }
}

// ================= cd: codedist, own dispatch for per-role timing =================
// 256 blocks x 256 threads, 4 target codes per block: e scanned once per 4 rows
// (e-traffic 268MB -> 64MB vs R6). Exact fp32 diff-square, second-min incl. diag(=0).
__global__ __launch_bounds__(256) void k_cd(const float* __restrict__ e,
                                            float* __restrict__ out_scales) {
    __shared__ float ek[4][DD];
    __shared__ float r0s[4][4], r1s[4][4];   // [wave][ki]
    __shared__ float sc[4];
    const int tid = threadIdx.x;
    const int w = tid >> 6, lane = tid & 63;
    const int kb = blockIdx.x * 4;
    {
        int ki = tid & 3, d = tid >> 2;       // d 0..63, two passes
        ek[ki][d]      = e[(size_t)d * KC + kb + ki];
        ek[ki][d + 64] = e[(size_t)(d + 64) * KC + kb + ki];
    }
    __syncthreads();
    const int j0 = tid * 4;
    float da[4][4];
    #pragma unroll
    for (int ki = 0; ki < 4; ki++)
        #pragma unroll
        for (int jj = 0; jj < 4; jj++) da[ki][jj] = 0.f;
    #pragma unroll 2
    for (int d = 0; d < DD; d++) {
        float4 ev = *(const float4*)&e[(size_t)d * KC + j0];
        const float* evp = (const float*)&ev;
        #pragma unroll
        for (int ki = 0; ki < 4; ki++) {
            float ec = ek[ki][d];
            #pragma unroll
            for (int jj = 0; jj < 4; jj++) {
                float t = ec - evp[jj];
                da[ki][jj] = fmaf(t, t, da[ki][jj]);
            }
        }
    }
    float m0[4], m1[4];
    #pragma unroll
    for (int ki = 0; ki < 4; ki++) {
        m0[ki] = FLT_BIG; m1[ki] = FLT_BIG;
        #pragma unroll
        for (int jj = 0; jj < 4; jj++) {
            float dd = da[ki][jj];
            if (dd < m0[ki]) { m1[ki] = m0[ki]; m0[ki] = dd; }
            else if (dd < m1[ki]) m1[ki] = dd;
        }
    }
    #pragma unroll
    for (int msk = 1; msk < 64; msk <<= 1) {
        #pragma unroll
        for (int ki = 0; ki < 4; ki++) {
            float u0 = __shfl_xor(m0[ki], msk, 64);
            float u1 = __shfl_xor(m1[ki], msk, 64);
            if (u0 < m0[ki]) { m1[ki] = fminf(m0[ki], u1); m0[ki] = u0; }
            else             { m1[ki] = fminf(m1[ki], u0); }
        }
    }
    if (lane == 0) {
        #pragma unroll
        for (int ki = 0; ki < 4; ki++) { r0s[w][ki] = m0[ki]; r1s[w][ki] = m1[ki]; }
    }
    __syncthreads();
    if (tid < 4) {
        float a0 = r0s[0][tid], a1 = r1s[0][tid];
        #pragma unroll
        for (int ww = 1; ww < 4; ww++) {
            float b0 = r0s[ww][tid], b1 = r1s[ww][tid];
            if (b0 < a0) { a1 = fminf(a0, b1); a0 = b0; }
            else         { a1 = fminf(a1, b0); }
        }
        sc[tid] = a1 * (1.0f / 64.0f);        // second_smallest / (D/2)
    }
    __syncthreads();
    {
        int d = tid & 127, r = tid >> 7;      // r = 0..1
        out_scales[(size_t)(kb + r) * DD + d]     = sc[r];
        out_scales[(size_t)(kb + r + 2) * DD + d] = sc[r + 2];
    }
}

// ======== main: persistent over K-half. 512 blocks = 2/CU exactly (R3 verified). ========
__global__ __launch_bounds__(256, 2) void k_main(const float* __restrict__ x,
                                                 const unsigned short* __restrict__ a_sw,
                                                 const float* __restrict__ s2g,
                                                 float* __restrict__ pv0,
                                                 float* __restrict__ pv1,
                                                 int* __restrict__ pi0) {
    __shared__ short es[2][16384];   // 2 x 32 KB double buffer
    __shared__ float s2s[512];

    const int tid = threadIdx.x;
    const int w = tid >> 6, lane = tid & 63;
    const int halfk = lane >> 5, col = lane & 31;
    const int gh = blockIdx.x & 1;          // K half: codes [gh*512, gh*512+512)
    const int rg = blockIdx.x >> 1;         // row group 0..255
    const int myrow = rg * 128 + w * 32 + col;

    {
        const char* src = (const char*)a_sw + (size_t)(gh * 8) * 32768;
        char* dst = (char*)&es[0][0];
        #pragma unroll
        for (int it = 0; it < 8; it++) {
            int off = (it * 256 + tid) * 16;
            __builtin_amdgcn_global_load_lds((gp1_t)(const void*)(src + off),
                                             (lp3_t)(void*)(dst + off), 16, 0, 0);
        }
    }
    s2s[tid]       = s2g[gh * 512 + tid];
    s2s[tid + 256] = s2g[gh * 512 + 256 + tid];

    const float* xr = x + (size_t)myrow * DD;
    bf16x8 xh[8], xl[8];
    #pragma unroll
    for (int kd = 0; kd < 8; kd++) {
        const float* p = xr + kd * 16 + halfk * 8;
        float4 a = *(const float4*)p;
        float4 b = *(const float4*)(p + 4);
        float v[8] = {a.x, a.y, a.z, a.w, b.x, b.y, b.z, b.w};
        #pragma unroll
        for (int j = 0; j < 8; j++) {
            unsigned short h = f2bf(v[j]);
            xh[kd][j] = (short)h;
            xl[kd][j] = (short)f2bf(v[j] - bf2f(h));
        }
    }
    __syncthreads();   // chunk 0 staged + s2s ready

    float bv0 = FLT_BIG, bv1 = FLT_BIG;
    int bi0 = 0x7fffffff;

    #pragma unroll 1
    for (int c = 0; c < 8; c++) {
        const int cb = c & 1;
        if (c < 7) {
            const char* src = (const char*)a_sw + (size_t)(gh * 8 + c + 1) * 32768;
            char* dst = (char*)&es[cb ^ 1][0];
            #pragma unroll
            for (int it = 0; it < 8; it++) {
                int off = (it * 256 + tid) * 16;
                __builtin_amdgcn_global_load_lds((gp1_t)(const void*)(src + off),
                                                 (lp3_t)(void*)(dst + off), 16, 0, 0);
            }
        }

        #pragma unroll 1
        for (int ct = 0; ct < 2; ct++) {
            f32x16 accA, accB, accC;
            #pragma unroll
            for (int r = 0; r < 16; r++) { accA[r] = 0.f; accB[r] = 0.f; accC[r] = 0.f; }

            #pragma unroll
            for (int kd = 0; kd < 8; kd++) {
                const short* fp = &es[cb][((ct * 8 + kd) * 2) * 512 + lane * 8];
                bf16x8 ahi = *(const bf16x8*)fp;
                bf16x8 alo = *(const bf16x8*)(fp + 512);
                accA = __builtin_amdgcn_mfma_f32_32x32x16_bf16(ahi, xh[kd], accA, 0, 0, 0);
                accB = __builtin_amdgcn_mfma_f32_32x32x16_bf16(alo, xh[kd], accB, 0, 0, 0);
                accC = __builtin_amdgcn_mfma_f32_32x32x16_bf16(ahi, xl[kd], accC, 0, 0, 0);
            }

            int lcb = c * 64 + ct * 32 + 4 * halfk;   // local code base 0..511
            #pragma unroll
            for (int g8 = 0; g8 < 4; g8++) {
                float4 s2v = *(const float4*)&s2s[lcb + g8 * 8];
                const float* s2p = (const float*)&s2v;
                #pragma unroll
                for (int q = 0; q < 4; q++) {
                    int r = g8 * 4 + q;
                    float sim = (accA[r] + accB[r]) + accC[r];
                    float dv = fmaf(-2.f, sim, s2p[q]);
                    int ci = gh * 512 + lcb + g8 * 8 + q;
                    bool lt = dv < bv0;
                    bv1 = fminf(bv1, fmaxf(bv0, dv));
                    bv0 = fminf(bv0, dv);
                    bi0 = lt ? ci : bi0;
                }
            }
        }
        __syncthreads();   // drains next-chunk staging + protects buffer reuse
    }

    float u0 = __shfl_xor(bv0, 32, 64);
    float u1 = __shfl_xor(bv1, 32, 64);
    int   j0 = __shfl_xor(bi0, 32, 64);
    float v0, v1; int i0;
    if (u0 < bv0 || (u0 == bv0 && j0 < bi0)) { v0 = u0; i0 = j0; v1 = fminf(u1, bv0); }
    else                                     { v0 = bv0; i0 = bi0; v1 = fminf(bv1, u0); }

    if (lane < 32) {
        size_t o = (size_t)myrow * 2 + gh;    // 2 partials per row
        pv0[o] = v0; pv1[o] = v1; pi0[o] = i0;
    }
}

// ============ post: gather-only (R3 structure). 2048 blocks x 128 thr, 16 rows. ============
__global__ __launch_bounds__(128) void k_post(const float* __restrict__ x,
                                              const float* __restrict__ e,
                                              const float* __restrict__ eT,
                                              const float* __restrict__ s2g,
                                              const float* __restrict__ pv0,
                                              const float* __restrict__ pv1,
                                              const int* __restrict__ pi0,
                                              float* __restrict__ out_q,
                                              double* __restrict__ partial) {
    __shared__ int   flist_l[16];
    __shared__ int   cnt;
    __shared__ float xrow[DD];
    __shared__ float rv[2];
    __shared__ int   ri[2];
    __shared__ int   kfix;
    __shared__ float wsum[2];
    const int tid = threadIdx.x;
    const int w = tid >> 6, lane = tid & 63;
    const int row0 = blockIdx.x * 16;
    const int rl = tid >> 3;                 // local row 0..15
    const int seg = (tid & 7) * 16;          // 16 consecutive floats

    if (tid == 0) cnt = 0;

    const size_t grow = (size_t)(row0 + rl);
    float4 xv[4];
    {
        const float* xp = x + grow * DD + seg;
        #pragma unroll
        for (int i = 0; i < 4; i++) xv[i] = *(const float4*)(xp + i * 4);
    }

    // ---- merge 2 half-partials (gh=0 indices lower, tie keeps first) ----
    float v0, v1; int i0;
    {
        size_t o = grow * 2;
        float a0 = pv0[o],     a1 = pv1[o];     int ai = pi0[o];
        float b0 = pv0[o + 1], b1 = pv1[o + 1]; int bi = pi0[o + 1];
        if (b0 < a0) { v0 = b0; i0 = bi; v1 = fminf(b1, a0); }
        else         { v0 = a0; i0 = ai; v1 = fminf(a1, b0); }
    }
    const int flagged = (v1 - v0 < EPS_GAP) ? 1 : 0;
    if ((tid & 7) == 0 && flagged) { int s = atomicAdd(&cnt, 1); flist_l[s] = rl; }

    float lsum = 0.f;
    if (!flagged) {
        const float* qp = eT + (size_t)i0 * DD + seg;
        float* op = out_q + grow * DD + seg;
        #pragma unroll
        for (int i = 0; i < 4; i++) {
            float4 q = *(const float4*)(qp + i * 4);
            *(float4*)(op + i * 4) = q;
            float f0 = q.x - xv[i].x, f1 = q.y - xv[i].y;
            float f2 = q.z - xv[i].z, f3 = q.w - xv[i].w;
            lsum = fmaf(f0, f0, lsum); lsum = fmaf(f1, f1, lsum);
            lsum = fmaf(f2, f2, lsum); lsum = fmaf(f3, f3, lsum);
        }
    }
    __syncthreads();

    // ---- exact fp32 re-argmin for flagged rows (rare, block-uniform) ----
    const int nf = cnt;
    for (int fi = 0; fi < nf; fi++) {
        const int r = flist_l[fi];
        if (tid < 32) ((float4*)xrow)[tid] = ((const float4*)(x + (size_t)(row0 + r) * DD))[tid];
        __syncthreads();
        int c0 = tid * 8;
        float s[8];
        #pragma unroll
        for (int j = 0; j < 8; j++) s[j] = 0.f;
        #pragma unroll 8
        for (int d = 0; d < DD; d++) {
            float xd = xrow[d];
            float4 ev0 = *(const float4*)(e + (size_t)d * KC + c0);
            float4 ev1 = *(const float4*)(e + (size_t)d * KC + c0 + 4);
            s[0] = fmaf(xd, ev0.x, s[0]); s[1] = fmaf(xd, ev0.y, s[1]);
            s[2] = fmaf(xd, ev0.z, s[2]); s[3] = fmaf(xd, ev0.w, s[3]);
            s[4] = fmaf(xd, ev1.x, s[4]); s[5] = fmaf(xd, ev1.y, s[5]);
            s[6] = fmaf(xd, ev1.z, s[6]); s[7] = fmaf(xd, ev1.w, s[7]);
        }
        float bv = FLT_BIG; int bi = 0x7fffffff;
        #pragma unroll
        for (int j = 0; j < 8; j++) {
            float dv = s2g[c0 + j] - 2.f * s[j];
            if (dv < bv) { bv = dv; bi = c0 + j; }
        }
        // wave-parallel argmin (lowest index on ties)
        #pragma unroll
        for (int msk = 1; msk < 64; msk <<= 1) {
            float ub = __shfl_xor(bv, msk, 64);
            int   ui = __shfl_xor(bi, msk, 64);
            if (ub < bv || (ub == bv && ui < bi)) { bv = ub; bi = ui; }
        }
        if (lane == 0) { rv[w] = bv; ri[w] = bi; }
        __syncthreads();
        if (tid == 0)
            kfix = (rv[1] < rv[0] || (rv[1] == rv[0] && ri[1] < ri[0])) ? ri[1] : ri[0];
        __syncthreads();
        {
            float q = eT[(size_t)kfix * DD + tid];
            float xd = xrow[tid];
            out_q[(size_t)(row0 + r) * DD + tid] = q;
            float f = q - xd;
            lsum = fmaf(f, f, lsum);
        }
        __syncthreads();
    }

    // ---- per-block partial loss: plain store, no atomics, no fence ----
    #pragma unroll
    for (int off = 32; off > 0; off >>= 1) lsum += __shfl_down(lsum, off, 64);
    if (lane == 0) wsum[w] = lsum;
    __syncthreads();
    if (tid == 0)
        partial[blockIdx.x] = (double)(wsum[0] + wsum[1]);
}

// ================= fin: sum 2048 partials, write loss =================
__global__ __launch_bounds__(256) void k_fin(const double* __restrict__ partial,
                                             float* __restrict__ out_loss) {
    __shared__ double wred[4];
    const int tid = threadIdx.x;
    const int w = tid >> 6, lane = tid & 63;
    double s = 0.0;
    #pragma unroll
    for (int i = 0; i < 8; i++) s += partial[i * 256 + tid];
    #pragma unroll
    for (int off = 32; off > 0; off >>= 1)
        s += __shfl_down(s, off, 64);
    if (lane == 0) wred[w] = s;
    __syncthreads();
    if (tid == 0) {
        double m = ((wred[0] + wred[1]) + (wred[2] + wred[3])) / 4194304.0;
        out_loss[0] = (float)(0.25 * m + m);
    }
}

extern "C" void kernel_launch(void* const* d_in, const int* in_sizes, int n_in,
                              void* d_out, int out_size, void* d_ws, size_t ws_size,
                              hipStream_t stream) {
    const float* x = (const float*)d_in[0];
    const float* e = (const float*)d_in[1];
    float* out_q      = (float*)d_out;
    float* out_loss   = out_q + (size_t)NROWS * DD;
    float* out_scales = out_loss + 1;

    char* ws = (char*)d_ws;
    float*  s2g            = (float*)(ws + 1024);
    float*  eT             = (float*)(ws + 8192);
    unsigned short* a_sw   = (unsigned short*)(ws + 532480);
    float*  pv0            = (float*)(ws + 1056768);   // 32768*2*4 = 256 KB
    float*  pv1            = (float*)(ws + 1318912);   // 256 KB
    int*    pi0            = (int*)(ws + 1581056);     // 256 KB
    double* partial        = (double*)(ws + 1843200);  // 2048*8 = 16 KB

    k_prep<<<132, 256, 0, stream>>>(e, a_sw, eT, s2g);
    k_cd<<<256, 256, 0, stream>>>(e, out_scales);
    k_main<<<512, 256, 0, stream>>>(x, a_sw, s2g, pv0, pv1, pi0);
    k_post<<<2048, 128, 0, stream>>>(x, e, eT, s2g, pv0, pv1, pi0, out_q, partial);
    k_fin<<<1, 256, 0, stream>>>(partial, out_loss);
}

// Round 8
// 140.730 us; speedup vs baseline: 1.5140x; 1.0300x over previous
//
#include <hip/hip_runtime.h>

typedef __attribute__((ext_vector_type(8))) short bf16x8;
typedef __attribute__((ext_vector_type(16))) float f32x16;

#define NROWS 32768
#define KC 1024
#define DD 128
#define EPS_GAP 2.5e-4f
#define FLT_BIG 3.4e38f

typedef const unsigned int __attribute__((address_space(1)))* gp1_t;
typedef unsigned int __attribute__((address_space(3)))* lp3_t;

__device__ __forceinline__ unsigned short f2bf(float f) {
    unsigned u = __float_as_uint(f);
    unsigned r = u + 0x7FFFu + ((u >> 16) & 1u);
    return (unsigned short)(r >> 16);
}
__device__ __forceinline__ float bf2f(unsigned short h) {
    return __uint_as_float(((unsigned)h) << 16);
}

// ========== prep+cd fused: 388 blocks. 0..127 tiles, 128..131 s2, 132..387 codedist ==========
__global__ __launch_bounds__(256) void k_prep_cd(const float* __restrict__ e,
                                                 unsigned short* __restrict__ a_sw,
                                                 float* __restrict__ eT,
                                                 float* __restrict__ s2g,
                                                 float* __restrict__ out_scales) {
    const int b = blockIdx.x, tid = threadIdx.x;
    if (b < 128) {
        const int t = b * 2 + (tid >> 7);     // tile 0..255
        const int ct = t >> 3, kd = t & 7;
        const int tt = tid & 127;
        const int m = tt & 31, dg = tt >> 5;
        const int c = ct * 32 + m;
        const int d0 = kd * 16 + dg * 4;
        float v[4]; short hi[4], lo[4];
        #pragma unroll
        for (int jj = 0; jj < 4; jj++) {
            float f = e[(size_t)(d0 + jj) * KC + c];
            v[jj] = f;
            unsigned short hh = f2bf(f);
            hi[jj] = (short)hh;
            lo[jj] = (short)f2bf(f - bf2f(hh));
        }
        const int h = dg >> 1, jb = (dg & 1) * 4;
        size_t base = ((size_t)(ct * 8 + kd) * 2) * 512 + (h * 32 + m) * 8 + jb;
        *(short4*)&a_sw[base]       = make_short4(hi[0], hi[1], hi[2], hi[3]);
        *(short4*)&a_sw[base + 512] = make_short4(lo[0], lo[1], lo[2], lo[3]);
        *(float4*)&eT[(size_t)c * DD + d0] = make_float4(v[0], v[1], v[2], v[3]);
    } else if (b < 132) {
        const int c = (b - 128) * 256 + tid;
        float s = 0.f;
        #pragma unroll 8
        for (int d = 0; d < DD; d++) { float f = e[(size_t)d * KC + c]; s = fmaf(f, f, s); }
        s2g[c] = s;
    } else {
        // ---- codedist role (R7-verified): 4 target codes/block, exact fp32 ----
        __shared__ float ek[4][DD];
        __shared__ float r0s[4][4], r1s[4][4];   // [wave][ki]
        __shared__ float sc[4];
        const int w = tid >> 6, lane = tid & 63;
        const int kb = (b - 132) * 4;
        {
            int ki = tid & 3, d = tid >> 2;       // d 0..63, two passes
            ek[ki][d]      = e[(size_t)d * KC + kb + ki];
            ek[ki][d + 64] = e[(size_t)(d + 64) * KC + kb + ki];
        }
        __syncthreads();
        const int j0 = tid * 4;
        float da[4][4];
        #pragma unroll
        for (int ki = 0; ki < 4; ki++)
            #pragma unroll
            for (int jj = 0; jj < 4; jj++) da[ki][jj] = 0.f;
        #pragma unroll 2
        for (int d = 0; d < DD; d++) {
            float4 ev = *(const float4*)&e[(size_t)d * KC + j0];
            const float* evp = (const float*)&ev;
            #pragma unroll
            for (int ki = 0; ki < 4; ki++) {
                float ec = ek[ki][d];
                #pragma unroll
                for (int jj = 0; jj < 4; jj++) {
                    float t = ec - evp[jj];
                    da[ki][jj] = fmaf(t, t, da[ki][jj]);
                }
            }
        }
        float m0[4], m1[4];
        #pragma unroll
        for (int ki = 0; ki < 4; ki++) {
            m0[ki] = FLT_BIG; m1[ki] = FLT_BIG;
            #pragma unroll
            for (int jj = 0; jj < 4; jj++) {
                float dd = da[ki][jj];
                if (dd < m0[ki]) { m1[ki] = m0[ki]; m0[ki] = dd; }
                else if (dd < m1[ki]) m1[ki] = dd;
            }
        }
        #pragma unroll
        for (int msk = 1; msk < 64; msk <<= 1) {
            #pragma unroll
            for (int ki = 0; ki < 4; ki++) {
                float u0 = __shfl_xor(m0[ki], msk, 64);
                float u1 = __shfl_xor(m1[ki], msk, 64);
                if (u0 < m0[ki]) { m1[ki] = fminf(m0[ki], u1); m0[ki] = u0; }
                else             { m1[ki] = fminf(m1[ki], u0); }
            }
        }
        if (lane == 0) {
            #pragma unroll
            for (int ki = 0; ki < 4; ki++) { r0s[w][ki] = m0[ki]; r1s[w][ki] = m1[ki]; }
        }
        __syncthreads();
        if (tid < 4) {
            float a0 = r0s[0][tid], a1 = r1s[0][tid];
            #pragma unroll
            for (int ww = 1; ww < 4; ww++) {
                float b0 = r0s[ww][tid], b1 = r1s[ww][tid];
                if (b0 < a0) { a1 = fminf(a0, b1); a0 = b0; }
                else         { a1 = fminf(a1, b0); }
            }
            sc[tid] = a1 * (1.0f / 64.0f);        // second_smallest / (D/2)
        }
        __syncthreads();
        {
            int d = tid & 127, r = tid >> 7;      // r = 0..1
            out_scales[(size_t)(kb + r) * DD + d]     = sc[r];
            out_scales[(size_t)(kb + r + 2) * DD + d] = sc[r + 2];
        }
    }
}

// ======== main: persistent over K-half. 512 blocks = 2/CU exactly (R3 verified). ========
// Changes vs R3: fmed3 second-min update; packed float4 partial store.
__global__ __launch_bounds__(256, 2) void k_main(const float* __restrict__ x,
                                                 const unsigned short* __restrict__ a_sw,
                                                 const float* __restrict__ s2g,
                                                 float4* __restrict__ pvq) {
    __shared__ short es[2][16384];   // 2 x 32 KB double buffer
    __shared__ float s2s[512];

    const int tid = threadIdx.x;
    const int w = tid >> 6, lane = tid & 63;
    const int halfk = lane >> 5, col = lane & 31;
    const int gh = blockIdx.x & 1;          // K half: codes [gh*512, gh*512+512)
    const int rg = blockIdx.x >> 1;         // row group 0..255
    const int myrow = rg * 128 + w * 32 + col;

    {
        const char* src = (const char*)a_sw + (size_t)(gh * 8) * 32768;
        char* dst = (char*)&es[0][0];
        #pragma unroll
        for (int it = 0; it < 8; it++) {
            int off = (it * 256 + tid) * 16;
            __builtin_amdgcn_global_load_lds((gp1_t)(const void*)(src + off),
                                             (lp3_t)(void*)(dst + off), 16, 0, 0);
        }
    }
    s2s[tid]       = s2g[gh * 512 + tid];
    s2s[tid + 256] = s2g[gh * 512 + 256 + tid];

    const float* xr = x + (size_t)myrow * DD;
    bf16x8 xh[8], xl[8];
    #pragma unroll
    for (int kd = 0; kd < 8; kd++) {
        const float* p = xr + kd * 16 + halfk * 8;
        float4 a = *(const float4*)p;
        float4 b = *(const float4*)(p + 4);
        float v[8] = {a.x, a.y, a.z, a.w, b.x, b.y, b.z, b.w};
        #pragma unroll
        for (int j = 0; j < 8; j++) {
            unsigned short h = f2bf(v[j]);
            xh[kd][j] = (short)h;
            xl[kd][j] = (short)f2bf(v[j] - bf2f(h));
        }
    }
    __syncthreads();   // chunk 0 staged + s2s ready

    float bv0 = FLT_BIG, bv1 = FLT_BIG;
    int bi0 = 0x7fffffff;

    #pragma unroll 1
    for (int c = 0; c < 8; c++) {
        const int cb = c & 1;
        if (c < 7) {
            const char* src = (const char*)a_sw + (size_t)(gh * 8 + c + 1) * 32768;
            char* dst = (char*)&es[cb ^ 1][0];
            #pragma unroll
            for (int it = 0; it < 8; it++) {
                int off = (it * 256 + tid) * 16;
                __builtin_amdgcn_global_load_lds((gp1_t)(const void*)(src + off),
                                                 (lp3_t)(void*)(dst + off), 16, 0, 0);
            }
        }

        #pragma unroll 1
        for (int ct = 0; ct < 2; ct++) {
            f32x16 accA, accB, accC;
            #pragma unroll
            for (int r = 0; r < 16; r++) { accA[r] = 0.f; accB[r] = 0.f; accC[r] = 0.f; }

            #pragma unroll
            for (int kd = 0; kd < 8; kd++) {
                const short* fp = &es[cb][((ct * 8 + kd) * 2) * 512 + lane * 8];
                bf16x8 ahi = *(const bf16x8*)fp;
                bf16x8 alo = *(const bf16x8*)(fp + 512);
                accA = __builtin_amdgcn_mfma_f32_32x32x16_bf16(ahi, xh[kd], accA, 0, 0, 0);
                accB = __builtin_amdgcn_mfma_f32_32x32x16_bf16(alo, xh[kd], accB, 0, 0, 0);
                accC = __builtin_amdgcn_mfma_f32_32x32x16_bf16(ahi, xl[kd], accC, 0, 0, 0);
            }

            int lcb = c * 64 + ct * 32 + 4 * halfk;   // local code base 0..511
            #pragma unroll
            for (int g8 = 0; g8 < 4; g8++) {
                float4 s2v = *(const float4*)&s2s[lcb + g8 * 8];
                const float* s2p = (const float*)&s2v;
                #pragma unroll
                for (int q = 0; q < 4; q++) {
                    int r = g8 * 4 + q;
                    float sim = (accA[r] + accB[r]) + accC[r];
                    float dv = fmaf(-2.f, sim, s2p[q]);
                    int ci = gh * 512 + lcb + g8 * 8 + q;
                    bool lt = dv < bv0;
                    // bv1' = median(bv0, bv1, dv): covers all three orderings exactly
                    bv1 = __builtin_amdgcn_fmed3f(bv0, bv1, dv);
                    bv0 = fminf(bv0, dv);
                    bi0 = lt ? ci : bi0;
                }
            }
        }
        __syncthreads();   // drains next-chunk staging + protects buffer reuse
    }

    float u0 = __shfl_xor(bv0, 32, 64);
    float u1 = __shfl_xor(bv1, 32, 64);
    int   j0 = __shfl_xor(bi0, 32, 64);
    float v0, v1; int i0;
    if (u0 < bv0 || (u0 == bv0 && j0 < bi0)) { v0 = u0; i0 = j0; v1 = fminf(u1, bv0); }
    else                                     { v0 = bv0; i0 = bi0; v1 = fminf(bv1, u0); }

    if (lane < 32)
        pvq[(size_t)myrow * 2 + gh] = make_float4(v0, v1, __int_as_float(i0), 0.f);
}

// ============ post: gather-only. 2048 blocks x 128 thr, 16 rows. Packed pv loads. ============
__global__ __launch_bounds__(128) void k_post(const float* __restrict__ x,
                                              const float* __restrict__ e,
                                              const float* __restrict__ eT,
                                              const float* __restrict__ s2g,
                                              const float4* __restrict__ pvq,
                                              float* __restrict__ out_q,
                                              double* __restrict__ partial) {
    __shared__ int   flist_l[16];
    __shared__ int   cnt;
    __shared__ float xrow[DD];
    __shared__ float rv[2];
    __shared__ int   ri[2];
    __shared__ int   kfix;
    __shared__ float wsum[2];
    const int tid = threadIdx.x;
    const int w = tid >> 6, lane = tid & 63;
    const int row0 = blockIdx.x * 16;
    const int rl = tid >> 3;                 // local row 0..15
    const int seg = (tid & 7) * 16;          // 16 consecutive floats

    if (tid == 0) cnt = 0;

    const size_t grow = (size_t)(row0 + rl);
    float4 xv[4];
    {
        const float* xp = x + grow * DD + seg;
        #pragma unroll
        for (int i = 0; i < 4; i++) xv[i] = *(const float4*)(xp + i * 4);
    }

    // ---- merge 2 half-partials (gh=0 indices lower, tie keeps first) ----
    float v0, v1; int i0;
    {
        float4 qa = pvq[grow * 2];
        float4 qb = pvq[grow * 2 + 1];
        float a0 = qa.x, a1 = qa.y; int ai = __float_as_int(qa.z);
        float b0 = qb.x, b1 = qb.y; int bi = __float_as_int(qb.z);
        if (b0 < a0) { v0 = b0; i0 = bi; v1 = fminf(b1, a0); }
        else         { v0 = a0; i0 = ai; v1 = fminf(a1, b0); }
    }
    const int flagged = (v1 - v0 < EPS_GAP) ? 1 : 0;
    if ((tid & 7) == 0 && flagged) { int s = atomicAdd(&cnt, 1); flist_l[s] = rl; }

    float lsum = 0.f;
    if (!flagged) {
        const float* qp = eT + (size_t)i0 * DD + seg;
        float* op = out_q + grow * DD + seg;
        #pragma unroll
        for (int i = 0; i < 4; i++) {
            float4 q = *(const float4*)(qp + i * 4);
            *(float4*)(op + i * 4) = q;
            float f0 = q.x - xv[i].x, f1 = q.y - xv[i].y;
            float f2 = q.z - xv[i].z, f3 = q.w - xv[i].w;
            lsum = fmaf(f0, f0, lsum); lsum = fmaf(f1, f1, lsum);
            lsum = fmaf(f2, f2, lsum); lsum = fmaf(f3, f3, lsum);
        }
    }
    __syncthreads();

    // ---- exact fp32 re-argmin for flagged rows (rare, block-uniform) ----
    const int nf = cnt;
    for (int fi = 0; fi < nf; fi++) {
        const int r = flist_l[fi];
        if (tid < 32) ((float4*)xrow)[tid] = ((const float4*)(x + (size_t)(row0 + r) * DD))[tid];
        __syncthreads();
        int c0 = tid * 8;
        float s[8];
        #pragma unroll
        for (int j = 0; j < 8; j++) s[j] = 0.f;
        #pragma unroll 16
        for (int d = 0; d < DD; d++) {
            float xd = xrow[d];
            float4 ev0 = *(const float4*)(e + (size_t)d * KC + c0);
            float4 ev1 = *(const float4*)(e + (size_t)d * KC + c0 + 4);
            s[0] = fmaf(xd, ev0.x, s[0]); s[1] = fmaf(xd, ev0.y, s[1]);
            s[2] = fmaf(xd, ev0.z, s[2]); s[3] = fmaf(xd, ev0.w, s[3]);
            s[4] = fmaf(xd, ev1.x, s[4]); s[5] = fmaf(xd, ev1.y, s[5]);
            s[6] = fmaf(xd, ev1.z, s[6]); s[7] = fmaf(xd, ev1.w, s[7]);
        }
        float bv = FLT_BIG; int bi = 0x7fffffff;
        #pragma unroll
        for (int j = 0; j < 8; j++) {
            float dv = s2g[c0 + j] - 2.f * s[j];
            if (dv < bv) { bv = dv; bi = c0 + j; }
        }
        // wave-parallel argmin (lowest index on ties)
        #pragma unroll
        for (int msk = 1; msk < 64; msk <<= 1) {
            float ub = __shfl_xor(bv, msk, 64);
            int   ui = __shfl_xor(bi, msk, 64);
            if (ub < bv || (ub == bv && ui < bi)) { bv = ub; bi = ui; }
        }
        if (lane == 0) { rv[w] = bv; ri[w] = bi; }
        __syncthreads();
        if (tid == 0)
            kfix = (rv[1] < rv[0] || (rv[1] == rv[0] && ri[1] < ri[0])) ? ri[1] : ri[0];
        __syncthreads();
        {
            float q = eT[(size_t)kfix * DD + tid];
            float xd = xrow[tid];
            out_q[(size_t)(row0 + r) * DD + tid] = q;
            float f = q - xd;
            lsum = fmaf(f, f, lsum);
        }
        __syncthreads();
    }

    // ---- per-block partial loss: plain store, no atomics, no fence ----
    #pragma unroll
    for (int off = 32; off > 0; off >>= 1) lsum += __shfl_down(lsum, off, 64);
    if (lane == 0) wsum[w] = lsum;
    __syncthreads();
    if (tid == 0)
        partial[blockIdx.x] = (double)(wsum[0] + wsum[1]);
}

// ================= fin: sum 2048 partials, write loss =================
__global__ __launch_bounds__(256) void k_fin(const double* __restrict__ partial,
                                             float* __restrict__ out_loss) {
    __shared__ double wred[4];
    const int tid = threadIdx.x;
    const int w = tid >> 6, lane = tid & 63;
    double s = 0.0;
    #pragma unroll
    for (int i = 0; i < 8; i++) s += partial[i * 256 + tid];
    #pragma unroll
    for (int off = 32; off > 0; off >>= 1)
        s += __shfl_down(s, off, 64);
    if (lane == 0) wred[w] = s;
    __syncthreads();
    if (tid == 0) {
        double m = ((wred[0] + wred[1]) + (wred[2] + wred[3])) / 4194304.0;
        out_loss[0] = (float)(0.25 * m + m);
    }
}

extern "C" void kernel_launch(void* const* d_in, const int* in_sizes, int n_in,
                              void* d_out, int out_size, void* d_ws, size_t ws_size,
                              hipStream_t stream) {
    const float* x = (const float*)d_in[0];
    const float* e = (const float*)d_in[1];
    float* out_q      = (float*)d_out;
    float* out_loss   = out_q + (size_t)NROWS * DD;
    float* out_scales = out_loss + 1;

    char* ws = (char*)d_ws;
    float*  s2g            = (float*)(ws + 1024);
    float*  eT             = (float*)(ws + 8192);
    unsigned short* a_sw   = (unsigned short*)(ws + 532480);
    float4* pvq            = (float4*)(ws + 1056768);  // 32768*2*16B = 1 MB
    double* partial        = (double*)(ws + 2105344);  // 2048*8 = 16 KB

    k_prep_cd<<<388, 256, 0, stream>>>(e, a_sw, eT, s2g, out_scales);
    k_main<<<512, 256, 0, stream>>>(x, a_sw, s2g, pvq);
    k_post<<<2048, 128, 0, stream>>>(x, e, eT, s2g, pvq, out_q, partial);
    k_fin<<<1, 256, 0, stream>>>(partial, out_loss);
}